// Round 2
// baseline (471.579 us; speedup 1.0000x reference)
//
#include <hip/hip_runtime.h>
#include <hip/hip_bf16.h>

// Problem: B=8, C=512, N=G*H*W=4096. All f32 in/out.
//   er = QrQr^T - QiQi^T ; ei = QrQi^T + (QrQi^T)^T   (B x C x C) -- BOTH SYMMETRIC
//   A  = softmax_row((rowmax(er)-er)^2 + (rowmax(ei)-ei)^2)   [near one-hot]
//   out = stack(g*A@Qr + xr, g*A@Qi + xi)
// Stage 1: split-bf16 MFMA (x = xh + xl; x*y ~ xh*yh + xh*yl + xl*yh, err ~2^-18)
// R2 changes vs 468us:
//   (a) nt stores for split-K partials + nt loads in softmax: partials (154MB) were
//       thrashing L3 (input 134MB + partials > 256MB) -> FETCH_SIZE 410MB = 3x unique.
//   (b) T14 prefetch rotation in energy + out k-loops: loads for t+1 issued after
//       barrier 2, consumed at t+1's LDS-write -> vmcnt(0) drain before barrier 1
//       now lands after a full MFMA phase instead of serializing load latency.
//   (c) LDS swizzle REVERTED (measured: conflicts 1.57e7 -> 1.84e7, swizzle lost).
//   (d) out_kernel: c-tile 256 (4 h-halves per staged Q tile) -> Q traffic halved.
#define B_ 8
#define C_ 512
#define N_ 4096
#define BK 32
#define NSPLIT 8
#define KCH (N_ / NSPLIT)
static const size_t PS = (size_t)B_ * C_ * C_;  // floats per partial buffer

typedef __bf16 bf16x8 __attribute__((ext_vector_type(8)));
typedef float f32x4 __attribute__((ext_vector_type(4)));

// 20 upper-triangle jobs: ci in 0..3 (128-row c-tile), dj in 0..7 (64-col d-tile), dj >= 2*ci
__device__ __constant__ unsigned char JCI[20] = {0,0,0,0,0,0,0,0, 1,1,1,1,1,1, 2,2,2,2, 3,3};
__device__ __constant__ unsigned char JDJ[20] = {0,1,2,3,4,5,6,7, 2,3,4,5,6,7, 4,5,6,7, 6,7};

__device__ __forceinline__ f32x4 mfma16(bf16x8 a, bf16x8 b, f32x4 c) {
    // A[m=lane&15][k=quad*8+j]; B[n=lane&15][k=quad*8+j]; D: col=lane&15, row=quad*4+reg
    return __builtin_amdgcn_mfma_f32_16x16x32_bf16(a, b, c, 0, 0, 0);
}

// pack two f32 -> bf16x2 word (RNE), lo in low half. Single VOP3 on gfx950.
__device__ __forceinline__ unsigned cvtpk_bf16(float lo, float hi) {
    unsigned r;
    asm("v_cvt_pk_bf16_f32 %0, %1, %2" : "=v"(r) : "v"(lo), "v"(hi));
    return r;
}

// split f32x4 -> hi (truncated bf16, exact remainder) + lo (RNE bf16 of remainder)
__device__ __forceinline__ void cvt_store4(const f32x4 v, __bf16* hp, __bf16* lp) {
    const unsigned u0 = __float_as_uint(v[0]), u1 = __float_as_uint(v[1]);
    const unsigned u2 = __float_as_uint(v[2]), u3 = __float_as_uint(v[3]);
    uint2 h, l;
    h.x = __builtin_amdgcn_perm(u1, u0, 0x07060302u);  // [u0.hi16 | u1.hi16]
    h.y = __builtin_amdgcn_perm(u3, u2, 0x07060302u);
    l.x = cvtpk_bf16(v[0] - __uint_as_float(u0 & 0xFFFF0000u),
                     v[1] - __uint_as_float(u1 & 0xFFFF0000u));
    l.y = cvtpk_bf16(v[2] - __uint_as_float(u2 & 0xFFFF0000u),
                     v[3] - __uint_as_float(u3 & 0xFFFF0000u));
    *(uint2*)hp = h;
    *(uint2*)lp = l;
}

// ---------------- Stage 1: energy partials via split-bf16 MFMA ---------------
// grid (job=20, split=8, b=8), block 256 (4 waves). Block tile 128(c) x 64(d);
// wave (wr,wc) owns 64x32 = 4x2 tiles of 16x16. LDS stride 40 (80 B rows).
// Loop rotated for T14 prefetch: store(t) | barrier | load(t+1) | frag+MFMA(t).
__global__ __launch_bounds__(256, 2) void energy_kernel(const float* __restrict__ x,
                                                        float* __restrict__ pbuf) {
    __shared__ __align__(16) __bf16 Ah[128][40], Al[128][40], Chs[128][40], Cls[128][40];
    __shared__ __align__(16) __bf16 Bh[64][40], Bl[64][40], Dh[64][40], Dl[64][40];
    const int b = blockIdx.z, sp = blockIdx.y;
    const int cbase = JCI[blockIdx.x] * 128, dbase = JDJ[blockIdx.x] * 64;
    const int t = threadIdx.x, lane = t & 63, wave = t >> 6;
    const int m = lane & 15, quad = lane >> 4;
    const int wr = wave >> 1, wc = wave & 1;

    const float* qr = x + (size_t)b * C_ * N_;
    const float* qi = qr + (size_t)B_ * C_ * N_;
    const int kbase = sp * KCH;

    const int a_row = t >> 1, a_k = (t & 1) * 16;  // A-panel: 2 thr/row, 16-k halves
    const int b_row = t >> 2, b_k = (t & 3) * 8;   // B-panel: 4 thr/row, 8-k quarters
    const float* agr = qr + (size_t)(cbase + a_row) * N_ + kbase + a_k;
    const float* agi = qi + (size_t)(cbase + a_row) * N_ + kbase + a_k;
    const float* bgr = qr + (size_t)(dbase + b_row) * N_ + kbase + b_k;
    const float* bgi = qi + (size_t)(dbase + b_row) * N_ + kbase + b_k;

    f32x4 accRR[4][2] = {}, accII[4][2] = {}, accEI[4][2] = {};
    f32x4 va[4], vc[4], vb[2], vd[2];

#define LOADK(kk)                                              \
    {                                                          \
        _Pragma("unroll") for (int u = 0; u < 4; ++u) {        \
            va[u] = *(const f32x4*)(agr + (kk) + u * 4);       \
            vc[u] = *(const f32x4*)(agi + (kk) + u * 4);       \
        }                                                      \
        _Pragma("unroll") for (int u = 0; u < 2; ++u) {        \
            vb[u] = *(const f32x4*)(bgr + (kk) + u * 4);       \
            vd[u] = *(const f32x4*)(bgi + (kk) + u * 4);       \
        }                                                      \
    }

    LOADK(0);
    for (int k0 = 0; k0 < KCH; k0 += BK) {
        __syncthreads();  // previous iteration's LDS reads done
#pragma unroll
        for (int u = 0; u < 4; ++u) {
            cvt_store4(va[u], &Ah[a_row][a_k + u * 4], &Al[a_row][a_k + u * 4]);
            cvt_store4(vc[u], &Chs[a_row][a_k + u * 4], &Cls[a_row][a_k + u * 4]);
        }
#pragma unroll
        for (int u = 0; u < 2; ++u) {
            cvt_store4(vb[u], &Bh[b_row][b_k + u * 4], &Bl[b_row][b_k + u * 4]);
            cvt_store4(vd[u], &Dh[b_row][b_k + u * 4], &Dl[b_row][b_k + u * 4]);
        }
        __syncthreads();

        // T14: issue next tile's loads now; they drain at next iteration's
        // first barrier, hidden under the fragment-read + MFMA phase below.
        const int kn = (k0 + BK < KCH) ? k0 + BK : 0;  // clamp: last iter redundant
        LOADK(kn);

        bf16x8 fBh[2], fBl[2], fDh[2], fDl[2];
#pragma unroll
        for (int j = 0; j < 2; ++j) {
            const int row = wc * 32 + j * 16 + m;
            fBh[j] = *(const bf16x8*)&Bh[row][quad * 8];
            fBl[j] = *(const bf16x8*)&Bl[row][quad * 8];
            fDh[j] = *(const bf16x8*)&Dh[row][quad * 8];
            fDl[j] = *(const bf16x8*)&Dl[row][quad * 8];
        }
#pragma unroll
        for (int i = 0; i < 4; ++i) {
            const int row = wr * 64 + i * 16 + m;
            const bf16x8 fAh = *(const bf16x8*)&Ah[row][quad * 8];
            const bf16x8 fAl = *(const bf16x8*)&Al[row][quad * 8];
            const bf16x8 fCh = *(const bf16x8*)&Chs[row][quad * 8];
            const bf16x8 fCl = *(const bf16x8*)&Cls[row][quad * 8];
#pragma unroll
            for (int j = 0; j < 2; ++j) {
                accRR[i][j] = mfma16(fAh, fBh[j], accRR[i][j]);
                accRR[i][j] = mfma16(fAh, fBl[j], accRR[i][j]);
                accRR[i][j] = mfma16(fAl, fBh[j], accRR[i][j]);
                accII[i][j] = mfma16(fCh, fDh[j], accII[i][j]);
                accII[i][j] = mfma16(fCh, fDl[j], accII[i][j]);
                accII[i][j] = mfma16(fCl, fDh[j], accII[i][j]);
                accEI[i][j] = mfma16(fAh, fDh[j], accEI[i][j]);
                accEI[i][j] = mfma16(fAh, fDl[j], accEI[i][j]);
                accEI[i][j] = mfma16(fAl, fDh[j], accEI[i][j]);
                accEI[i][j] = mfma16(fCh, fBh[j], accEI[i][j]);
                accEI[i][j] = mfma16(fCh, fBl[j], accEI[i][j]);
                accEI[i][j] = mfma16(fCl, fBh[j], accEI[i][j]);
            }
        }
    }
#undef LOADK

    // nt stores: partials are write-once/read-once -> keep them out of L3 so the
    // panel re-reads (983 MB logical) stay L3-resident.
    float* per = pbuf + (size_t)(2 * sp) * PS + (size_t)b * C_ * C_;
    float* pei = per + PS;
#pragma unroll
    for (int i = 0; i < 4; ++i)
#pragma unroll
        for (int j = 0; j < 2; ++j) {
            const int c0 = cbase + wr * 64 + i * 16 + quad * 4;  // 4-aligned
            const int d = dbase + wc * 32 + j * 16 + m;
            const f32x4 e = accRR[i][j] - accII[i][j];
            const f32x4 f = accEI[i][j];
#pragma unroll
            for (int r = 0; r < 4; ++r) {  // direct (coalesced over m)
                __builtin_nontemporal_store(e[r], per + (size_t)(c0 + r) * C_ + d);
                __builtin_nontemporal_store(f[r], pei + (size_t)(c0 + r) * C_ + d);
            }
            // mirror (lower triangle): row d, cols c0..c0+3, 16B vector store
            __builtin_nontemporal_store(e, (f32x4*)(per + (size_t)d * C_ + c0));
            __builtin_nontemporal_store(f, (f32x4*)(pei + (size_t)d * C_ + c0));
        }
}

// ---------------- Stage 2: fold split-K partials + softmax -------------------
__device__ __forceinline__ float waveMax(float v) {
#pragma unroll
    for (int off = 32; off > 0; off >>= 1) v = fmaxf(v, __shfl_xor(v, off));
    return v;
}
__device__ __forceinline__ float waveSum(float v) {
#pragma unroll
    for (int off = 32; off > 0; off >>= 1) v += __shfl_xor(v, off);
    return v;
}

// grid (c=512, b=8), block 256 -> one row of 512 per block, 2 elems/thread.
__global__ __launch_bounds__(256) void softmax_kernel(const float* __restrict__ pbuf,
                                                      __bf16* __restrict__ att) {
    __shared__ float buf[4];
    const int b = blockIdx.y, c = blockIdx.x, t = threadIdx.x;
    const int wave = t >> 6, lane = t & 63;
    const size_t rbase = ((size_t)(b * C_ + c)) * C_;

    float er0 = 0.f, er1 = 0.f, ei0 = 0.f, ei1 = 0.f;
#pragma unroll
    for (int s = 0; s < NSPLIT; ++s) {
        const float* per = pbuf + (size_t)(2 * s) * PS;
        const float* pei = per + PS;
        er0 += __builtin_nontemporal_load(per + rbase + t);
        er1 += __builtin_nontemporal_load(per + rbase + t + 256);
        ei0 += __builtin_nontemporal_load(pei + rbase + t);
        ei1 += __builtin_nontemporal_load(pei + rbase + t + 256);
    }

    float v = waveMax(fmaxf(er0, er1));
    if (lane == 0) buf[wave] = v;
    __syncthreads();
    const float mer = fmaxf(fmaxf(buf[0], buf[1]), fmaxf(buf[2], buf[3]));
    __syncthreads();

    v = waveMax(fmaxf(ei0, ei1));
    if (lane == 0) buf[wave] = v;
    __syncthreads();
    const float mei = fmaxf(fmaxf(buf[0], buf[1]), fmaxf(buf[2], buf[3]));
    __syncthreads();

    const float a0 = mer - er0, c0 = mei - ei0;
    const float a1 = mer - er1, c1 = mei - ei1;
    const float t0 = a0 * a0 + c0 * c0;
    const float t1 = a1 * a1 + c1 * c1;

    v = waveMax(fmaxf(t0, t1));
    if (lane == 0) buf[wave] = v;
    __syncthreads();
    const float mt = fmaxf(fmaxf(buf[0], buf[1]), fmaxf(buf[2], buf[3]));
    __syncthreads();

    const float e0 = expf(t0 - mt), e1 = expf(t1 - mt);
    v = waveSum(e0 + e1);
    if (lane == 0) buf[wave] = v;
    __syncthreads();
    const float s = buf[0] + buf[1] + buf[2] + buf[3];
    const float inv = 1.0f / s;

    att[rbase + t] = (__bf16)(e0 * inv);
    att[rbase + t + 256] = (__bf16)(e1 * inv);
}

// ---------------- Stage 3: out = g * (A @ Q) + x, bf16 MFMA ------------------
// grid (nt=64, ct=2, b=8), block 256. 256(c) x 64(n) tile, K=512 over d.
// Four 64-c halves per block share each staged Q tile (Q k-loop traffic 537->270MB).
// Same T14 prefetch rotation as stage 1.
__global__ __launch_bounds__(256, 2) void out_kernel(const float* __restrict__ x,
                                                     const __bf16* __restrict__ att,
                                                     const float* __restrict__ gamma,
                                                     float* __restrict__ out) {
    __shared__ __align__(16) unsigned Lr[64 * 20];
    __shared__ __align__(16) unsigned Li[64 * 20];
    const int b = blockIdx.z, ct = blockIdx.y, nt = blockIdx.x;
    const int t = threadIdx.x, lane = t & 63, wave = t >> 6;
    const int m = lane & 15, quad = lane >> 4;

    const float* qr = x + (size_t)b * C_ * N_;
    const float* qi = qr + (size_t)B_ * C_ * N_;
    const int cbase = ct * 256;
    const __bf16* arow = att + ((size_t)(b * C_ + cbase + wave * 16 + m)) * C_ + quad * 8;

    const int kp = t & 15;        // k-pair index: k = 2kp, 2kp+1
    const int n4 = (t >> 4) * 4;  // n group 0,4,..,60
    const int n0 = nt * 64;

    f32x4 accr[4][4] = {}, acci[4][4] = {};
    f32x4 pr0, pr1, pi0, pi1;
    bf16x8 pa[4];

#define LOADO(kk)                                                                \
    {                                                                            \
        pr0 = *(const f32x4*)(qr + (size_t)((kk) + 2 * kp) * N_ + n0 + n4);      \
        pr1 = *(const f32x4*)(qr + (size_t)((kk) + 2 * kp + 1) * N_ + n0 + n4);  \
        pi0 = *(const f32x4*)(qi + (size_t)((kk) + 2 * kp) * N_ + n0 + n4);      \
        pi1 = *(const f32x4*)(qi + (size_t)((kk) + 2 * kp + 1) * N_ + n0 + n4);  \
        _Pragma("unroll") for (int h = 0; h < 4; ++h)                            \
            pa[h] = *(const bf16x8*)(arow + (size_t)(h * 64) * C_ + (kk));       \
    }

    LOADO(0);
    for (int kk = 0; kk < C_; kk += 32) {
        const f32x4 r0 = pr0, r1 = pr1, i0 = pi0, i1 = pi1;
        bf16x8 a[4];
#pragma unroll
        for (int h = 0; h < 4; ++h) a[h] = pa[h];
        __syncthreads();  // previous iteration's LDS reads done
#pragma unroll
        for (int u = 0; u < 4; ++u) {
            Lr[(n4 + u) * 20 + kp] = cvtpk_bf16(r0[u], r1[u]);
            Li[(n4 + u) * 20 + kp] = cvtpk_bf16(i0[u], i1[u]);
        }
        __syncthreads();

        const int kn = (kk + 32 < C_) ? kk + 32 : 0;  // clamp: last iter redundant
        LOADO(kn);
#pragma unroll
        for (int s = 0; s < 4; ++s) {
            const bf16x8 br = *(const bf16x8*)(&Lr[(s * 16 + m) * 20 + quad * 4]);
            const bf16x8 bi = *(const bf16x8*)(&Li[(s * 16 + m) * 20 + quad * 4]);
#pragma unroll
            for (int h = 0; h < 4; ++h) {
                accr[h][s] = mfma16(a[h], br, accr[h][s]);
                acci[h][s] = mfma16(a[h], bi, acci[h][s]);
            }
        }
    }
#undef LOADO

    const float g = gamma[0];
    float* outr = out + (size_t)b * C_ * N_;
    float* outi = outr + (size_t)B_ * C_ * N_;
#pragma unroll
    for (int h = 0; h < 4; ++h)
#pragma unroll
        for (int s = 0; s < 4; ++s)
#pragma unroll
            for (int r = 0; r < 4; ++r) {
                const int cc = cbase + h * 64 + wave * 16 + quad * 4 + r;
                const int nn = n0 + s * 16 + m;
                const size_t ix = (size_t)cc * N_ + nn;
                outr[ix] = g * accr[h][s][r] + qr[ix];
                outi[ix] = g * acci[h][s][r] + qi[ix];
            }
}

// -----------------------------------------------------------------------------
extern "C" void kernel_launch(void* const* d_in, const int* in_sizes, int n_in,
                              void* d_out, int out_size, void* d_ws, size_t ws_size,
                              hipStream_t stream) {
    const float* x = (const float*)d_in[0];
    const float* gamma = (const float*)d_in[1];
    float* out = (float*)d_out;

    // Split-K partials (2*NSPLIT x 8.4 MB = 134 MB) live in d_out (134 MB exactly),
    // which stage 3 overwrites afterwards. ws holds only att (4.2 MB bf16).
    float* pbuf = out;
    __bf16* att = (__bf16*)d_ws;

    energy_kernel<<<dim3(20, NSPLIT, B_), 256, 0, stream>>>(x, pbuf);
    softmax_kernel<<<dim3(C_, B_), 256, 0, stream>>>(pbuf, att);
    out_kernel<<<dim3(64, 2, 8), 256, 0, stream>>>(x, att, gamma, out);
}

// Round 3
// 443.119 us; speedup vs baseline: 1.0642x; 1.0642x over previous
//
#include <hip/hip_runtime.h>
#include <hip/hip_bf16.h>

// Problem: B=8, C=512, N=G*H*W=4096. All f32 in/out.
//   er = QrQr^T - QiQi^T ; ei = QrQi^T + (QrQi^T)^T   (B x C x C) -- BOTH SYMMETRIC
//   A  = softmax_row((rowmax(er)-er)^2 + (rowmax(ei)-ei)^2)
//   out = stack(g*A@Qr + xr, g*A@Qi + xi)
// Stage 1: split-bf16 MFMA (x = xh + xl; x*y ~ xh*yh + xh*yl + xl*yh, err ~2^-18)
// R3 changes vs 471us (R2):
//   (a) energy RETILE 128x64 -> 64x64: 36 upper-tri jobs x8x8 = 2304 blocks =
//       EXACTLY 3 rounds at 3 blocks/CU (was 2.5 rounds @ 2/CU, 83% packing).
//       LDS 41KB, acc 48 AGPR -> 12 waves/CU (was 8). Diag waste 25%->12%.
//   (b) energy nt-stores and T14 rotation REVERTED (measured: +20us regression;
//       WRITE_SIZE 154->202MB, nt lost L2 write-combining).
//   (c) conflict chase dropped: SQ_LDS_BANK_CONFLICT invariant to swizzle (1.835e7
//       both ways) => dominated by benign 2-way b128 read aliasing (free).
//   (d) out_kernel keeps R2's 256-c tile (measured -17us).
#define B_ 8
#define C_ 512
#define N_ 4096
#define BK 32
#define NSPLIT 8
#define KCH (N_ / NSPLIT)
static const size_t PS = (size_t)B_ * C_ * C_;  // floats per partial buffer

typedef __bf16 bf16x8 __attribute__((ext_vector_type(8)));
typedef float f32x4 __attribute__((ext_vector_type(4)));

// 36 upper-triangle jobs: ci,dj in 0..7 (64x64 tiles), dj >= ci
__device__ __constant__ unsigned char JCI[36] = {
    0,0,0,0,0,0,0,0, 1,1,1,1,1,1,1, 2,2,2,2,2,2, 3,3,3,3,3, 4,4,4,4, 5,5,5, 6,6, 7};
__device__ __constant__ unsigned char JDJ[36] = {
    0,1,2,3,4,5,6,7, 1,2,3,4,5,6,7, 2,3,4,5,6,7, 3,4,5,6,7, 4,5,6,7, 5,6,7, 6,7, 7};

__device__ __forceinline__ f32x4 mfma16(bf16x8 a, bf16x8 b, f32x4 c) {
    // A[m=lane&15][k=quad*8+j]; B[n=lane&15][k=quad*8+j]; D: col=lane&15, row=quad*4+reg
    return __builtin_amdgcn_mfma_f32_16x16x32_bf16(a, b, c, 0, 0, 0);
}

// pack two f32 -> bf16x2 word (RNE), lo in low half. Single VOP3 on gfx950.
__device__ __forceinline__ unsigned cvtpk_bf16(float lo, float hi) {
    unsigned r;
    asm("v_cvt_pk_bf16_f32 %0, %1, %2" : "=v"(r) : "v"(lo), "v"(hi));
    return r;
}

// split f32x4 -> hi (truncated bf16, exact remainder) + lo (RNE bf16 of remainder)
__device__ __forceinline__ void cvt_store4(const f32x4 v, __bf16* hp, __bf16* lp) {
    const unsigned u0 = __float_as_uint(v[0]), u1 = __float_as_uint(v[1]);
    const unsigned u2 = __float_as_uint(v[2]), u3 = __float_as_uint(v[3]);
    uint2 h, l;
    h.x = __builtin_amdgcn_perm(u1, u0, 0x07060302u);  // [u0.hi16 | u1.hi16]
    h.y = __builtin_amdgcn_perm(u3, u2, 0x07060302u);
    l.x = cvtpk_bf16(v[0] - __uint_as_float(u0 & 0xFFFF0000u),
                     v[1] - __uint_as_float(u1 & 0xFFFF0000u));
    l.y = cvtpk_bf16(v[2] - __uint_as_float(u2 & 0xFFFF0000u),
                     v[3] - __uint_as_float(u3 & 0xFFFF0000u));
    *(uint2*)hp = h;
    *(uint2*)lp = l;
}

// ---------------- Stage 1: energy partials via split-bf16 MFMA ---------------
// grid (job=36, split=8, b=8), block 256 (4 waves). Block tile 64(c) x 64(d);
// wave (wr,wc) owns 32x32 = 2x2 tiles of 16x16. LDS stride 40 (80 B rows).
// Staging: 4 thr/row, 8-float quarters -> b64 writes 2-way (free), b128 reads 2-way.
__global__ __launch_bounds__(256, 3) void energy_kernel(const float* __restrict__ x,
                                                        float* __restrict__ pbuf) {
    __shared__ __align__(16) __bf16 Ah[64][40], Al[64][40], Chs[64][40], Cls[64][40];
    __shared__ __align__(16) __bf16 Bh[64][40], Bl[64][40], Dh[64][40], Dl[64][40];
    const int b = blockIdx.z, sp = blockIdx.y;
    const int cbase = JCI[blockIdx.x] * 64, dbase = JDJ[blockIdx.x] * 64;
    const int t = threadIdx.x, lane = t & 63, wave = t >> 6;
    const int m = lane & 15, quad = lane >> 4;
    const int wr = wave >> 1, wc = wave & 1;

    const float* qr = x + (size_t)b * C_ * N_;
    const float* qi = qr + (size_t)B_ * C_ * N_;
    const int kbase = sp * KCH;

    const int s_row = t >> 2, s_k = (t & 3) * 8;  // 4 thr/row, 8-float quarters
    const float* agr = qr + (size_t)(cbase + s_row) * N_ + kbase + s_k;
    const float* agi = qi + (size_t)(cbase + s_row) * N_ + kbase + s_k;
    const float* bgr = qr + (size_t)(dbase + s_row) * N_ + kbase + s_k;
    const float* bgi = qi + (size_t)(dbase + s_row) * N_ + kbase + s_k;

    f32x4 accRR[2][2] = {}, accII[2][2] = {}, accEI[2][2] = {};

    for (int k0 = 0; k0 < KCH; k0 += BK) {
        f32x4 va[2], vc[2], vb[2], vd[2];
#pragma unroll
        for (int u = 0; u < 2; ++u) {
            va[u] = *(const f32x4*)(agr + k0 + u * 4);
            vc[u] = *(const f32x4*)(agi + k0 + u * 4);
            vb[u] = *(const f32x4*)(bgr + k0 + u * 4);
            vd[u] = *(const f32x4*)(bgi + k0 + u * 4);
        }
        __syncthreads();  // previous iteration's LDS reads done
#pragma unroll
        for (int u = 0; u < 2; ++u) {
            cvt_store4(va[u], &Ah[s_row][s_k + u * 4], &Al[s_row][s_k + u * 4]);
            cvt_store4(vc[u], &Chs[s_row][s_k + u * 4], &Cls[s_row][s_k + u * 4]);
            cvt_store4(vb[u], &Bh[s_row][s_k + u * 4], &Bl[s_row][s_k + u * 4]);
            cvt_store4(vd[u], &Dh[s_row][s_k + u * 4], &Dl[s_row][s_k + u * 4]);
        }
        __syncthreads();

        bf16x8 fBh[2], fBl[2], fDh[2], fDl[2];
#pragma unroll
        for (int j = 0; j < 2; ++j) {
            const int row = wc * 32 + j * 16 + m;
            fBh[j] = *(const bf16x8*)&Bh[row][quad * 8];
            fBl[j] = *(const bf16x8*)&Bl[row][quad * 8];
            fDh[j] = *(const bf16x8*)&Dh[row][quad * 8];
            fDl[j] = *(const bf16x8*)&Dl[row][quad * 8];
        }
#pragma unroll
        for (int i = 0; i < 2; ++i) {
            const int row = wr * 32 + i * 16 + m;
            const bf16x8 fAh = *(const bf16x8*)&Ah[row][quad * 8];
            const bf16x8 fAl = *(const bf16x8*)&Al[row][quad * 8];
            const bf16x8 fCh = *(const bf16x8*)&Chs[row][quad * 8];
            const bf16x8 fCl = *(const bf16x8*)&Cls[row][quad * 8];
#pragma unroll
            for (int j = 0; j < 2; ++j) {
                accRR[i][j] = mfma16(fAh, fBh[j], accRR[i][j]);
                accRR[i][j] = mfma16(fAh, fBl[j], accRR[i][j]);
                accRR[i][j] = mfma16(fAl, fBh[j], accRR[i][j]);
                accII[i][j] = mfma16(fCh, fDh[j], accII[i][j]);
                accII[i][j] = mfma16(fCh, fDl[j], accII[i][j]);
                accII[i][j] = mfma16(fCl, fDh[j], accII[i][j]);
                accEI[i][j] = mfma16(fAh, fDh[j], accEI[i][j]);
                accEI[i][j] = mfma16(fAh, fDl[j], accEI[i][j]);
                accEI[i][j] = mfma16(fAl, fDh[j], accEI[i][j]);
                accEI[i][j] = mfma16(fCh, fBh[j], accEI[i][j]);
                accEI[i][j] = mfma16(fCh, fBl[j], accEI[i][j]);
                accEI[i][j] = mfma16(fCl, fBh[j], accEI[i][j]);
            }
        }
    }

    float* per = pbuf + (size_t)(2 * sp) * PS + (size_t)b * C_ * C_;
    float* pei = per + PS;
#pragma unroll
    for (int i = 0; i < 2; ++i)
#pragma unroll
        for (int j = 0; j < 2; ++j) {
            const int c0 = cbase + wr * 32 + i * 16 + quad * 4;  // 4-aligned
            const int d = dbase + wc * 32 + j * 16 + m;
            const f32x4 e = accRR[i][j] - accII[i][j];
            const f32x4 f = accEI[i][j];
#pragma unroll
            for (int r = 0; r < 4; ++r) {  // direct (coalesced over m)
                per[(size_t)(c0 + r) * C_ + d] = e[r];
                pei[(size_t)(c0 + r) * C_ + d] = f[r];
            }
            // mirror (lower triangle): row d, cols c0..c0+3, 16B vector store
            *(f32x4*)(per + (size_t)d * C_ + c0) = e;
            *(f32x4*)(pei + (size_t)d * C_ + c0) = f;
        }
}

// ---------------- Stage 2: fold split-K partials + softmax -------------------
__device__ __forceinline__ float waveMax(float v) {
#pragma unroll
    for (int off = 32; off > 0; off >>= 1) v = fmaxf(v, __shfl_xor(v, off));
    return v;
}
__device__ __forceinline__ float waveSum(float v) {
#pragma unroll
    for (int off = 32; off > 0; off >>= 1) v += __shfl_xor(v, off);
    return v;
}

// grid (c=512, b=8), block 256 -> one row of 512 per block, 2 elems/thread.
__global__ __launch_bounds__(256) void softmax_kernel(const float* __restrict__ pbuf,
                                                      __bf16* __restrict__ att) {
    __shared__ float buf[4];
    const int b = blockIdx.y, c = blockIdx.x, t = threadIdx.x;
    const int wave = t >> 6, lane = t & 63;
    const size_t rbase = ((size_t)(b * C_ + c)) * C_;

    float er0 = 0.f, er1 = 0.f, ei0 = 0.f, ei1 = 0.f;
#pragma unroll
    for (int s = 0; s < NSPLIT; ++s) {
        const float* per = pbuf + (size_t)(2 * s) * PS;
        const float* pei = per + PS;
        er0 += per[rbase + t];
        er1 += per[rbase + t + 256];
        ei0 += pei[rbase + t];
        ei1 += pei[rbase + t + 256];
    }

    float v = waveMax(fmaxf(er0, er1));
    if (lane == 0) buf[wave] = v;
    __syncthreads();
    const float mer = fmaxf(fmaxf(buf[0], buf[1]), fmaxf(buf[2], buf[3]));
    __syncthreads();

    v = waveMax(fmaxf(ei0, ei1));
    if (lane == 0) buf[wave] = v;
    __syncthreads();
    const float mei = fmaxf(fmaxf(buf[0], buf[1]), fmaxf(buf[2], buf[3]));
    __syncthreads();

    const float a0 = mer - er0, c0 = mei - ei0;
    const float a1 = mer - er1, c1 = mei - ei1;
    const float t0 = a0 * a0 + c0 * c0;
    const float t1 = a1 * a1 + c1 * c1;

    v = waveMax(fmaxf(t0, t1));
    if (lane == 0) buf[wave] = v;
    __syncthreads();
    const float mt = fmaxf(fmaxf(buf[0], buf[1]), fmaxf(buf[2], buf[3]));
    __syncthreads();

    const float e0 = expf(t0 - mt), e1 = expf(t1 - mt);
    v = waveSum(e0 + e1);
    if (lane == 0) buf[wave] = v;
    __syncthreads();
    const float s = buf[0] + buf[1] + buf[2] + buf[3];
    const float inv = 1.0f / s;

    att[rbase + t] = (__bf16)(e0 * inv);
    att[rbase + t + 256] = (__bf16)(e1 * inv);
}

// ---------------- Stage 3: out = g * (A @ Q) + x, bf16 MFMA ------------------
// grid (nt=64, ct=2, b=8), block 256. 256(c) x 64(n) tile, K=512 over d.
// Four 64-c halves per block share each staged Q tile.
__global__ __launch_bounds__(256, 2) void out_kernel(const float* __restrict__ x,
                                                     const __bf16* __restrict__ att,
                                                     const float* __restrict__ gamma,
                                                     float* __restrict__ out) {
    __shared__ __align__(16) unsigned Lr[64 * 20];
    __shared__ __align__(16) unsigned Li[64 * 20];
    const int b = blockIdx.z, ct = blockIdx.y, nt = blockIdx.x;
    const int t = threadIdx.x, lane = t & 63, wave = t >> 6;
    const int m = lane & 15, quad = lane >> 4;

    const float* qr = x + (size_t)b * C_ * N_;
    const float* qi = qr + (size_t)B_ * C_ * N_;
    const int cbase = ct * 256;
    const __bf16* arow = att + ((size_t)(b * C_ + cbase + wave * 16 + m)) * C_ + quad * 8;

    const int kp = t & 15;        // k-pair index: k = 2kp, 2kp+1
    const int n4 = (t >> 4) * 4;  // n group 0,4,..,60
    const int n0 = nt * 64;

    f32x4 accr[4][4] = {}, acci[4][4] = {};
    f32x4 pr0, pr1, pi0, pi1;
    bf16x8 pa[4];

#define LOADO(kk)                                                                \
    {                                                                            \
        pr0 = *(const f32x4*)(qr + (size_t)((kk) + 2 * kp) * N_ + n0 + n4);      \
        pr1 = *(const f32x4*)(qr + (size_t)((kk) + 2 * kp + 1) * N_ + n0 + n4);  \
        pi0 = *(const f32x4*)(qi + (size_t)((kk) + 2 * kp) * N_ + n0 + n4);      \
        pi1 = *(const f32x4*)(qi + (size_t)((kk) + 2 * kp + 1) * N_ + n0 + n4);  \
        _Pragma("unroll") for (int h = 0; h < 4; ++h)                            \
            pa[h] = *(const bf16x8*)(arow + (size_t)(h * 64) * C_ + (kk));       \
    }

    LOADO(0);
    for (int kk = 0; kk < C_; kk += 32) {
        const f32x4 r0 = pr0, r1 = pr1, i0 = pi0, i1 = pi1;
        bf16x8 a[4];
#pragma unroll
        for (int h = 0; h < 4; ++h) a[h] = pa[h];
        __syncthreads();  // previous iteration's LDS reads done
#pragma unroll
        for (int u = 0; u < 4; ++u) {
            Lr[(n4 + u) * 20 + kp] = cvtpk_bf16(r0[u], r1[u]);
            Li[(n4 + u) * 20 + kp] = cvtpk_bf16(i0[u], i1[u]);
        }
        __syncthreads();

        const int kn = (kk + 32 < C_) ? kk + 32 : 0;  // clamp: last iter redundant
        LOADO(kn);
#pragma unroll
        for (int s = 0; s < 4; ++s) {
            const bf16x8 br = *(const bf16x8*)(&Lr[(s * 16 + m) * 20 + quad * 4]);
            const bf16x8 bi = *(const bf16x8*)(&Li[(s * 16 + m) * 20 + quad * 4]);
#pragma unroll
            for (int h = 0; h < 4; ++h) {
                accr[h][s] = mfma16(a[h], br, accr[h][s]);
                acci[h][s] = mfma16(a[h], bi, acci[h][s]);
            }
        }
    }
#undef LOADO

    const float g = gamma[0];
    float* outr = out + (size_t)b * C_ * N_;
    float* outi = outr + (size_t)B_ * C_ * N_;
#pragma unroll
    for (int h = 0; h < 4; ++h)
#pragma unroll
        for (int s = 0; s < 4; ++s)
#pragma unroll
            for (int r = 0; r < 4; ++r) {
                const int cc = cbase + h * 64 + wave * 16 + quad * 4 + r;
                const int nn = n0 + s * 16 + m;
                const size_t ix = (size_t)cc * N_ + nn;
                outr[ix] = g * accr[h][s][r] + qr[ix];
                outi[ix] = g * acci[h][s][r] + qi[ix];
            }
}

// -----------------------------------------------------------------------------
extern "C" void kernel_launch(void* const* d_in, const int* in_sizes, int n_in,
                              void* d_out, int out_size, void* d_ws, size_t ws_size,
                              hipStream_t stream) {
    const float* x = (const float*)d_in[0];
    const float* gamma = (const float*)d_in[1];
    float* out = (float*)d_out;

    // Split-K partials (2*NSPLIT x 8.4 MB = 134 MB) live in d_out (134 MB exactly),
    // which stage 3 overwrites afterwards. ws holds only att (4.2 MB bf16).
    float* pbuf = out;
    __bf16* att = (__bf16*)d_ws;

    energy_kernel<<<dim3(36, NSPLIT, B_), 256, 0, stream>>>(x, pbuf);
    softmax_kernel<<<dim3(C_, B_), 256, 0, stream>>>(pbuf, att);
    out_kernel<<<dim3(64, 2, 8), 256, 0, stream>>>(x, att, gamma, out);
}

// Round 4
// 422.806 us; speedup vs baseline: 1.1154x; 1.0480x over previous
//
#include <hip/hip_runtime.h>
#include <hip/hip_bf16.h>

// Problem: B=8, C=512, N=G*H*W=4096. All f32 in/out.
//   er = QrQr^T - QiQi^T ; ei = QrQi^T + (QrQi^T)^T   (B x C x C) -- BOTH SYMMETRIC
//   A  = softmax_row((rowmax(er)-er)^2 + (rowmax(ei)-ei)^2)
//   out = stack(g*A@Qr + xr, g*A@Qi + xi)
// Stage 1: split-bf16 MFMA (x = xh + xl; x*y ~ xh*yh + xh*yl + xl*yh, err ~2^-18)
// R4 changes vs 443us (R3):
//   (a) energy XCD-chunked swizzle (bijective: 2304 = 8*288): all 8 sp-groups of
//       batch b land on XCD b. Each group's 2MB panel set becomes L2-resident and
//       is fetched ONCE (was ~8x: round-robin scattered groups -> FETCH 478MB =
//       3.7x unique; staging loads were ~900cy HBM-class -> the measured stall).
//   (b) out_kernel LDS double-buffer: 1 barrier/k-iter (WAR barrier removed).
//   (c) softmax: float2 loads (halve load count), 8 -> 3 barriers, packed
//       bf16x2 att store. Numerically identical (RNE / assoc-max unchanged).
#define B_ 8
#define C_ 512
#define N_ 4096
#define BK 32
#define NSPLIT 8
#define KCH (N_ / NSPLIT)
static const size_t PS = (size_t)B_ * C_ * C_;  // floats per partial buffer

typedef __bf16 bf16x8 __attribute__((ext_vector_type(8)));
typedef float f32x4 __attribute__((ext_vector_type(4)));

// 36 upper-triangle jobs: ci,dj in 0..7 (64x64 tiles), dj >= ci
__device__ __constant__ unsigned char JCI[36] = {
    0,0,0,0,0,0,0,0, 1,1,1,1,1,1,1, 2,2,2,2,2,2, 3,3,3,3,3, 4,4,4,4, 5,5,5, 6,6, 7};
__device__ __constant__ unsigned char JDJ[36] = {
    0,1,2,3,4,5,6,7, 1,2,3,4,5,6,7, 2,3,4,5,6,7, 3,4,5,6,7, 4,5,6,7, 5,6,7, 6,7, 7};

__device__ __forceinline__ f32x4 mfma16(bf16x8 a, bf16x8 b, f32x4 c) {
    // A[m=lane&15][k=quad*8+j]; B[n=lane&15][k=quad*8+j]; D: col=lane&15, row=quad*4+reg
    return __builtin_amdgcn_mfma_f32_16x16x32_bf16(a, b, c, 0, 0, 0);
}

// pack two f32 -> bf16x2 word (RNE), lo in low half. Single VOP3 on gfx950.
__device__ __forceinline__ unsigned cvtpk_bf16(float lo, float hi) {
    unsigned r;
    asm("v_cvt_pk_bf16_f32 %0, %1, %2" : "=v"(r) : "v"(lo), "v"(hi));
    return r;
}

// split f32x4 -> hi (truncated bf16, exact remainder) + lo (RNE bf16 of remainder)
__device__ __forceinline__ void cvt_store4(const f32x4 v, __bf16* hp, __bf16* lp) {
    const unsigned u0 = __float_as_uint(v[0]), u1 = __float_as_uint(v[1]);
    const unsigned u2 = __float_as_uint(v[2]), u3 = __float_as_uint(v[3]);
    uint2 h, l;
    h.x = __builtin_amdgcn_perm(u1, u0, 0x07060302u);  // [u0.hi16 | u1.hi16]
    h.y = __builtin_amdgcn_perm(u3, u2, 0x07060302u);
    l.x = cvtpk_bf16(v[0] - __uint_as_float(u0 & 0xFFFF0000u),
                     v[1] - __uint_as_float(u1 & 0xFFFF0000u));
    l.y = cvtpk_bf16(v[2] - __uint_as_float(u2 & 0xFFFF0000u),
                     v[3] - __uint_as_float(u3 & 0xFFFF0000u));
    *(uint2*)hp = h;
    *(uint2*)lp = l;
}

// ---------------- Stage 1: energy partials via split-bf16 MFMA ---------------
// grid 2304 (flat, XCD-swizzled), block 256 (4 waves). Block tile 64(c) x 64(d);
// wave (wr,wc) owns 32x32 = 2x2 tiles of 16x16. LDS stride 40 (80 B rows).
__global__ __launch_bounds__(256, 3) void energy_kernel(const float* __restrict__ x,
                                                        float* __restrict__ pbuf) {
    __shared__ __align__(16) __bf16 Ah[64][40], Al[64][40], Chs[64][40], Cls[64][40];
    __shared__ __align__(16) __bf16 Bh[64][40], Bl[64][40], Dh[64][40], Dl[64][40];
    // XCD-chunked bijective swizzle: HW assigns dispatch i to XCD i%8; give XCD x
    // the logical range [288x, 288x+288) = all 8 sp-groups of batch b=x.
    const int bid = blockIdx.x;
    const int logical = (bid & 7) * 288 + (bid >> 3);
    const int job = logical % 36;
    const int grp = logical / 36;  // 0..63 = sp + 8*b
    const int sp = grp & 7, b = grp >> 3;

    const int cbase = JCI[job] * 64, dbase = JDJ[job] * 64;
    const int t = threadIdx.x, lane = t & 63, wave = t >> 6;
    const int m = lane & 15, quad = lane >> 4;
    const int wr = wave >> 1, wc = wave & 1;

    const float* qr = x + (size_t)b * C_ * N_;
    const float* qi = qr + (size_t)B_ * C_ * N_;
    const int kbase = sp * KCH;

    const int s_row = t >> 2, s_k = (t & 3) * 8;  // 4 thr/row, 8-float quarters
    const float* agr = qr + (size_t)(cbase + s_row) * N_ + kbase + s_k;
    const float* agi = qi + (size_t)(cbase + s_row) * N_ + kbase + s_k;
    const float* bgr = qr + (size_t)(dbase + s_row) * N_ + kbase + s_k;
    const float* bgi = qi + (size_t)(dbase + s_row) * N_ + kbase + s_k;

    f32x4 accRR[2][2] = {}, accII[2][2] = {}, accEI[2][2] = {};

    for (int k0 = 0; k0 < KCH; k0 += BK) {
        f32x4 va[2], vc[2], vb[2], vd[2];
#pragma unroll
        for (int u = 0; u < 2; ++u) {
            va[u] = *(const f32x4*)(agr + k0 + u * 4);
            vc[u] = *(const f32x4*)(agi + k0 + u * 4);
            vb[u] = *(const f32x4*)(bgr + k0 + u * 4);
            vd[u] = *(const f32x4*)(bgi + k0 + u * 4);
        }
        __syncthreads();  // previous iteration's LDS reads done
#pragma unroll
        for (int u = 0; u < 2; ++u) {
            cvt_store4(va[u], &Ah[s_row][s_k + u * 4], &Al[s_row][s_k + u * 4]);
            cvt_store4(vc[u], &Chs[s_row][s_k + u * 4], &Cls[s_row][s_k + u * 4]);
            cvt_store4(vb[u], &Bh[s_row][s_k + u * 4], &Bl[s_row][s_k + u * 4]);
            cvt_store4(vd[u], &Dh[s_row][s_k + u * 4], &Dl[s_row][s_k + u * 4]);
        }
        __syncthreads();

        bf16x8 fBh[2], fBl[2], fDh[2], fDl[2];
#pragma unroll
        for (int j = 0; j < 2; ++j) {
            const int row = wc * 32 + j * 16 + m;
            fBh[j] = *(const bf16x8*)&Bh[row][quad * 8];
            fBl[j] = *(const bf16x8*)&Bl[row][quad * 8];
            fDh[j] = *(const bf16x8*)&Dh[row][quad * 8];
            fDl[j] = *(const bf16x8*)&Dl[row][quad * 8];
        }
#pragma unroll
        for (int i = 0; i < 2; ++i) {
            const int row = wr * 32 + i * 16 + m;
            const bf16x8 fAh = *(const bf16x8*)&Ah[row][quad * 8];
            const bf16x8 fAl = *(const bf16x8*)&Al[row][quad * 8];
            const bf16x8 fCh = *(const bf16x8*)&Chs[row][quad * 8];
            const bf16x8 fCl = *(const bf16x8*)&Cls[row][quad * 8];
#pragma unroll
            for (int j = 0; j < 2; ++j) {
                accRR[i][j] = mfma16(fAh, fBh[j], accRR[i][j]);
                accRR[i][j] = mfma16(fAh, fBl[j], accRR[i][j]);
                accRR[i][j] = mfma16(fAl, fBh[j], accRR[i][j]);
                accII[i][j] = mfma16(fCh, fDh[j], accII[i][j]);
                accII[i][j] = mfma16(fCh, fDl[j], accII[i][j]);
                accII[i][j] = mfma16(fCl, fDh[j], accII[i][j]);
                accEI[i][j] = mfma16(fAh, fDh[j], accEI[i][j]);
                accEI[i][j] = mfma16(fAh, fDl[j], accEI[i][j]);
                accEI[i][j] = mfma16(fAl, fDh[j], accEI[i][j]);
                accEI[i][j] = mfma16(fCh, fBh[j], accEI[i][j]);
                accEI[i][j] = mfma16(fCh, fBl[j], accEI[i][j]);
                accEI[i][j] = mfma16(fCl, fBh[j], accEI[i][j]);
            }
        }
    }

    float* per = pbuf + (size_t)(2 * sp) * PS + (size_t)b * C_ * C_;
    float* pei = per + PS;
#pragma unroll
    for (int i = 0; i < 2; ++i)
#pragma unroll
        for (int j = 0; j < 2; ++j) {
            const int c0 = cbase + wr * 32 + i * 16 + quad * 4;  // 4-aligned
            const int d = dbase + wc * 32 + j * 16 + m;
            const f32x4 e = accRR[i][j] - accII[i][j];
            const f32x4 f = accEI[i][j];
#pragma unroll
            for (int r = 0; r < 4; ++r) {  // direct (coalesced over m)
                per[(size_t)(c0 + r) * C_ + d] = e[r];
                pei[(size_t)(c0 + r) * C_ + d] = f[r];
            }
            // mirror (lower triangle): row d, cols c0..c0+3, 16B vector store
            *(f32x4*)(per + (size_t)d * C_ + c0) = e;
            *(f32x4*)(pei + (size_t)d * C_ + c0) = f;
        }
}

// ---------------- Stage 2: fold split-K partials + softmax -------------------
__device__ __forceinline__ float waveMax(float v) {
#pragma unroll
    for (int off = 32; off > 0; off >>= 1) v = fmaxf(v, __shfl_xor(v, off));
    return v;
}
__device__ __forceinline__ float waveSum(float v) {
#pragma unroll
    for (int off = 32; off > 0; off >>= 1) v += __shfl_xor(v, off);
    return v;
}

// grid (c=512, b=8), block 256 -> one row of 512 per block, cols 2t,2t+1 per thread.
__global__ __launch_bounds__(256) void softmax_kernel(const float* __restrict__ pbuf,
                                                      __bf16* __restrict__ att) {
    __shared__ float bufA[4][2];
    __shared__ float bufB[4];
    __shared__ float bufC[4];
    const int b = blockIdx.y, c = blockIdx.x, t = threadIdx.x;
    const int wave = t >> 6, lane = t & 63;
    const size_t rbase = ((size_t)(b * C_ + c)) * C_;

    float erx = 0.f, ery = 0.f, eix = 0.f, eiy = 0.f;
#pragma unroll
    for (int s = 0; s < NSPLIT; ++s) {
        const float* per = pbuf + (size_t)(2 * s) * PS;
        const float* pei = per + PS;
        const float2 er = *(const float2*)(per + rbase + 2 * t);
        const float2 ei = *(const float2*)(pei + rbase + 2 * t);
        erx += er.x; ery += er.y;
        eix += ei.x; eiy += ei.y;
    }

    // phase 1: row maxes of er and ei (one barrier)
    float vr = waveMax(fmaxf(erx, ery));
    float vi = waveMax(fmaxf(eix, eiy));
    if (lane == 0) { bufA[wave][0] = vr; bufA[wave][1] = vi; }
    __syncthreads();
    const float mer = fmaxf(fmaxf(bufA[0][0], bufA[1][0]), fmaxf(bufA[2][0], bufA[3][0]));
    const float mei = fmaxf(fmaxf(bufA[0][1], bufA[1][1]), fmaxf(bufA[2][1], bufA[3][1]));

    const float a0 = mer - erx, c0 = mei - eix;
    const float a1 = mer - ery, c1 = mei - eiy;
    const float t0 = a0 * a0 + c0 * c0;
    const float t1 = a1 * a1 + c1 * c1;

    // phase 2: max of squared magnitude (one barrier)
    float v = waveMax(fmaxf(t0, t1));
    if (lane == 0) bufB[wave] = v;
    __syncthreads();
    const float mt = fmaxf(fmaxf(bufB[0], bufB[1]), fmaxf(bufB[2], bufB[3]));

    // phase 3: sum of exp (one barrier)
    const float e0 = expf(t0 - mt), e1 = expf(t1 - mt);
    v = waveSum(e0 + e1);
    if (lane == 0) bufC[wave] = v;
    __syncthreads();
    const float s = bufC[0] + bufC[1] + bufC[2] + bufC[3];
    const float inv = 1.0f / s;

    *(unsigned*)(att + rbase + 2 * t) = cvtpk_bf16(e0 * inv, e1 * inv);
}

// ---------------- Stage 3: out = g * (A @ Q) + x, bf16 MFMA ------------------
// grid (nt=64, ct=2, b=8), block 256. 256(c) x 64(n) tile, K=512 over d.
// Four 64-c halves per block share each staged Q tile. LDS double-buffered:
// write buf[cur] | LOADO(next) | barrier | MFMA from buf[cur]  -> 1 barrier/iter.
__global__ __launch_bounds__(256, 2) void out_kernel(const float* __restrict__ x,
                                                     const __bf16* __restrict__ att,
                                                     const float* __restrict__ gamma,
                                                     float* __restrict__ out) {
    __shared__ __align__(16) unsigned Lr[2][64 * 20];
    __shared__ __align__(16) unsigned Li[2][64 * 20];
    const int b = blockIdx.z, ct = blockIdx.y, nt = blockIdx.x;
    const int t = threadIdx.x, lane = t & 63, wave = t >> 6;
    const int m = lane & 15, quad = lane >> 4;

    const float* qr = x + (size_t)b * C_ * N_;
    const float* qi = qr + (size_t)B_ * C_ * N_;
    const int cbase = ct * 256;
    const __bf16* arow = att + ((size_t)(b * C_ + cbase + wave * 16 + m)) * C_ + quad * 8;

    const int kp = t & 15;        // k-pair index: k = 2kp, 2kp+1
    const int n4 = (t >> 4) * 4;  // n group 0,4,..,60
    const int n0 = nt * 64;

    f32x4 accr[4][4] = {}, acci[4][4] = {};
    f32x4 pr0, pr1, pi0, pi1;
    bf16x8 pa[4];

#define LOADO(kk)                                                                \
    {                                                                            \
        pr0 = *(const f32x4*)(qr + (size_t)((kk) + 2 * kp) * N_ + n0 + n4);      \
        pr1 = *(const f32x4*)(qr + (size_t)((kk) + 2 * kp + 1) * N_ + n0 + n4);  \
        pi0 = *(const f32x4*)(qi + (size_t)((kk) + 2 * kp) * N_ + n0 + n4);      \
        pi1 = *(const f32x4*)(qi + (size_t)((kk) + 2 * kp + 1) * N_ + n0 + n4);  \
        _Pragma("unroll") for (int h = 0; h < 4; ++h)                            \
            pa[h] = *(const bf16x8*)(arow + (size_t)(h * 64) * C_ + (kk));       \
    }

    LOADO(0);
    int cur = 0;
    for (int kk = 0; kk < C_; kk += 32) {
        const f32x4 r0 = pr0, r1 = pr1, i0 = pi0, i1 = pi1;
        bf16x8 a[4];
#pragma unroll
        for (int h = 0; h < 4; ++h) a[h] = pa[h];
#pragma unroll
        for (int u = 0; u < 4; ++u) {
            Lr[cur][(n4 + u) * 20 + kp] = cvtpk_bf16(r0[u], r1[u]);
            Li[cur][(n4 + u) * 20 + kp] = cvtpk_bf16(i0[u], i1[u]);
        }
        const int kn = (kk + 32 < C_) ? kk + 32 : 0;  // clamp: last iter redundant
        LOADO(kn);
        __syncthreads();  // buf[cur] writes visible; prev buf's reads were drained
                          // at each wave's own previous barrier (lgkmcnt(0))
#pragma unroll
        for (int s = 0; s < 4; ++s) {
            const bf16x8 br = *(const bf16x8*)(&Lr[cur][(s * 16 + m) * 20 + quad * 4]);
            const bf16x8 bi = *(const bf16x8*)(&Li[cur][(s * 16 + m) * 20 + quad * 4]);
#pragma unroll
            for (int h = 0; h < 4; ++h) {
                accr[h][s] = mfma16(a[h], br, accr[h][s]);
                acci[h][s] = mfma16(a[h], bi, acci[h][s]);
            }
        }
        cur ^= 1;
    }
#undef LOADO

    const float g = gamma[0];
    float* outr = out + (size_t)b * C_ * N_;
    float* outi = outr + (size_t)B_ * C_ * N_;
#pragma unroll
    for (int h = 0; h < 4; ++h)
#pragma unroll
        for (int s = 0; s < 4; ++s)
#pragma unroll
            for (int r = 0; r < 4; ++r) {
                const int cc = cbase + h * 64 + wave * 16 + quad * 4 + r;
                const int nn = n0 + s * 16 + m;
                const size_t ix = (size_t)cc * N_ + nn;
                outr[ix] = g * accr[h][s][r] + qr[ix];
                outi[ix] = g * acci[h][s][r] + qi[ix];
            }
}

// -----------------------------------------------------------------------------
extern "C" void kernel_launch(void* const* d_in, const int* in_sizes, int n_in,
                              void* d_out, int out_size, void* d_ws, size_t ws_size,
                              hipStream_t stream) {
    const float* x = (const float*)d_in[0];
    const float* gamma = (const float*)d_in[1];
    float* out = (float*)d_out;

    // Split-K partials (2*NSPLIT x 8.4 MB = 134 MB) live in d_out (134 MB exactly),
    // which stage 3 overwrites afterwards. ws holds only att (4.2 MB bf16).
    float* pbuf = out;
    __bf16* att = (__bf16*)d_ws;

    energy_kernel<<<dim3(36 * NSPLIT * B_), 256, 0, stream>>>(x, pbuf);
    softmax_kernel<<<dim3(C_, B_), 256, 0, stream>>>(pbuf, att);
    out_kernel<<<dim3(64, 2, 8), 256, 0, stream>>>(x, att, gamma, out);
}